// Round 9
// baseline (155.133 us; speedup 1.0000x reference)
//
#include <hip/hip_runtime.h>
#include <hip/hip_bf16.h>

// Decoder loss: keep-mask (kth-value threshold + local max), BCE coord loss,
// bidirectional NN recolor + L1 rgb loss.
// L=16384 candidates, N=10000 targets, K=8 (collapses to argmin; R1-proven).
// R9: 4 kernels. Rules learned on this part:
//   - grid.sync ~40us (R4); mass per-block __threadfence ~0.4ms (R7): NEVER.
//   - single-producer bounded spin is CHEAP (R7's k_selkeep was fine).
//   - LDS-tiled broadcast scans, not uniform global streams (R5: 7x slower).
//   - kernel boundary ~9-10us; worth one spin-fusion per boundary removed.

#define SCAN_T 256
typedef unsigned long long ull;

// ---- Kernel 1: init + monotone keys + per-8 local max ----------------------
__global__ __launch_bounds__(256) void k_prep(
    const float* __restrict__ pred, const float* __restrict__ txyz,
    float4* __restrict__ ttile, float4* __restrict__ numden,
    int* __restrict__ zerohit, ull* __restrict__ tmin, ull* __restrict__ fmin,
    unsigned int* __restrict__ key, unsigned char* __restrict__ islm,
    int* __restrict__ counters, float* __restrict__ out, int L, int N) {
  int gidx = blockIdx.x * 256 + threadIdx.x;
  int gsz = (int)gridDim.x * 256;
  for (int i = gidx; i < N; i += gsz) {
    float x = txyz[3*i], y = txyz[3*i+1], z = txyz[3*i+2];
    ttile[i] = make_float4(x, y, z, fmaf(x, x, fmaf(y, y, z * z)));
    tmin[i] = ~0ull;
  }
  for (int i = gidx; i < L; i += gsz) {
    numden[i] = make_float4(0.f, 0.f, 0.f, 0.f);
    zerohit[i] = 0;
    fmin[i] = ~0ull;
  }
  if (gidx < 8) counters[gidx] = 0;   // [0]=kcount [4]=scatter-done
  if (gidx < 2) out[gidx] = 0.f;
  int ngroups = L >> 3;
  for (int g = gidx; g < ngroups; g += gsz) {
    const float4* pv = (const float4*)pred + (size_t)g * 2;
    float4 a = pv[0], b = pv[1];
    float v[8] = {a.x, a.y, a.z, a.w, b.x, b.y, b.z, b.w};
    int bi = 0; float bv = v[0];
    #pragma unroll
    for (int j = 1; j < 8; ++j) if (v[j] > bv) { bv = v[j]; bi = j; }
    unsigned int kk[8];
    ull lmpack = 0ull;
    #pragma unroll
    for (int j = 0; j < 8; ++j) {
      unsigned int fb = __float_as_uint(v[j]);
      unsigned int mk = (fb & 0x80000000u) ? ~fb : (fb | 0x80000000u);
      if (j == bi) { mk = 0xFF800000u; lmpack |= 1ull << (8 * j); }  // +inf
      kk[j] = mk;
    }
    ((uint4*)key)[g*2]   = make_uint4(kk[0], kk[1], kk[2], kk[3]);
    ((uint4*)key)[g*2+1] = make_uint4(kk[4], kk[5], kk[6], kk[7]);
    *(ull*)(islm + (size_t)g * 8) = lmpack;
  }
}

// ---- helper: pick bin containing rank from LDS hist (wave 0) ---------------
__device__ __forceinline__ void select_bin(
    unsigned int* hist, int nb, unsigned int rank,
    unsigned int* sB, unsigned int* sR, int tid) {
  if (tid < 64) {
    int g = nb >> 6;
    unsigned int sum = 0;
    for (int j = 0; j < g; ++j) sum += hist[tid * g + j];
    unsigned int incl = sum;
    for (int o = 1; o < 64; o <<= 1) {
      unsigned int v = __shfl_up(incl, o);
      if (tid >= o) incl += v;
    }
    unsigned int excl = incl - sum;
    bool cond = (rank >= excl) && (rank < incl);
    unsigned long long bal = __ballot(cond);
    int first = __ffsll((long long)bal) - 1;
    if (tid == first) {
      unsigned int r = rank - excl, cum = 0;
      for (int j = 0; j < g; ++j) {
        unsigned int c = hist[tid * g + j];
        if (r < cum + c) { *sB = (unsigned int)(tid * g + j); *sR = r - cum; break; }
        cum += c;
      }
    }
  }
}

// ---- Kernel 2: last block selects threshold; all blocks keep/compact/BCE ---
// R7-proven single-producer spin (cheap). Flag poison 0xAA != sentinel 1.
__global__ __launch_bounds__(256) void k_selkeep(
    const float* __restrict__ pred, const unsigned int* __restrict__ key,
    const unsigned char* __restrict__ islm, const int* __restrict__ pnum_p,
    const float* __restrict__ cxyz, const int* __restrict__ ktgt,
    int* __restrict__ keep, float4* __restrict__ klist, int* __restrict__ kidx,
    int* __restrict__ counters, unsigned int* __restrict__ thrbits,
    unsigned int* __restrict__ flag, float* __restrict__ out, int L) {
  __shared__ unsigned int hist[2048];
  __shared__ unsigned int sB, sR;
  int tid = threadIdx.x;
  if (blockIdx.x == gridDim.x - 1) {
    unsigned int rank = (unsigned int)(L - pnum_p[0] - 1);
    const uint4* k4 = (const uint4*)key;
    int n4 = L >> 2;
    for (int b = tid; b < 2048; b += 256) hist[b] = 0u;
    __syncthreads();
    for (int i = tid; i < n4; i += 256) {
      uint4 v = k4[i];
      atomicAdd(&hist[v.x >> 21], 1u); atomicAdd(&hist[v.y >> 21], 1u);
      atomicAdd(&hist[v.z >> 21], 1u); atomicAdd(&hist[v.w >> 21], 1u);
    }
    __syncthreads();
    select_bin(hist, 2048, rank, &sB, &sR, tid);
    __syncthreads();
    unsigned int B1 = sB, R1 = sR;
    for (int b = tid; b < 2048; b += 256) hist[b] = 0u;
    __syncthreads();
    for (int i = tid; i < n4; i += 256) {
      uint4 v = k4[i];
      if ((v.x >> 21) == B1) atomicAdd(&hist[(v.x >> 10) & 2047u], 1u);
      if ((v.y >> 21) == B1) atomicAdd(&hist[(v.y >> 10) & 2047u], 1u);
      if ((v.z >> 21) == B1) atomicAdd(&hist[(v.z >> 10) & 2047u], 1u);
      if ((v.w >> 21) == B1) atomicAdd(&hist[(v.w >> 10) & 2047u], 1u);
    }
    __syncthreads();
    select_bin(hist, 2048, R1, &sB, &sR, tid);
    __syncthreads();
    unsigned int B2 = sB, R2 = sR;
    for (int b = tid; b < 1024; b += 256) hist[b] = 0u;
    __syncthreads();
    unsigned int top22 = (B1 << 11) | B2;
    for (int i = tid; i < n4; i += 256) {
      uint4 v = k4[i];
      if ((v.x >> 10) == top22) atomicAdd(&hist[v.x & 1023u], 1u);
      if ((v.y >> 10) == top22) atomicAdd(&hist[v.y & 1023u], 1u);
      if ((v.z >> 10) == top22) atomicAdd(&hist[v.z & 1023u], 1u);
      if ((v.w >> 10) == top22) atomicAdd(&hist[v.w & 1023u], 1u);
    }
    __syncthreads();
    select_bin(hist, 1024, R2, &sB, &sR, tid);
    __syncthreads();
    if (tid == 0) {
      unsigned int fkey = (B1 << 21) | (B2 << 10) | sB;
      unsigned int fb = (fkey & 0x80000000u) ? (fkey & 0x7FFFFFFFu) : ~fkey;
      atomicExch(thrbits, fb);
      __threadfence();
      atomicExch(flag, 1u);          // release
    }
  }
  if (tid == 0) {
    while (atomicAdd(flag, 0u) != 1u) __builtin_amdgcn_s_sleep(2);
  }
  __syncthreads();
  float thr = __uint_as_float(atomicAdd(thrbits, 0u));
  int i = blockIdx.x * 256 + tid;
  float term = 0.f;
  if (i < L) {
    float p = pred[i];
    bool kp = (p > thr) || islm[i];
    keep[i] = kp ? 1 : 0;
    if (kp) {
      int pos = atomicAdd(&counters[0], 1);   // order irrelevant (no ties)
      float x = cxyz[3*i], y = cxyz[3*i+1], z = cxyz[3*i+2];
      klist[pos] = make_float4(x, y, z, fmaf(x, x, fmaf(y, y, z * z)));
      kidx[pos] = i;
    }
    float t = (float)ktgt[i];
    term = fmaxf(p, 0.f) - p * t + log1pf(expf(-fabsf(p)));
  }
  for (int o = 32; o > 0; o >>= 1) term += __shfl_down(term, o);
  if ((tid & 63) == 0) atomicAdd(&out[0], term);
}

// ---- Kernel 3: dual-role scan (bwd y<YB, fwd y>=YB), 2-chain ILP -----------
__global__ __launch_bounds__(SCAN_T) void k_scan2(
    const float* __restrict__ txyz, const float4* __restrict__ klist,
    const int* __restrict__ kidx, const float4* __restrict__ ttile,
    const int* __restrict__ counters, ull* __restrict__ tmin,
    ull* __restrict__ fmin, int L, int N, int YB) {
  __shared__ float4 tile[SCAN_T];
  int tid = threadIdx.x, x = blockIdx.x, y = blockIdx.y;
  int kc = counters[0];

  if (y < YB) {
    // ---- backward: targets x*256.. vs kept-candidate chunk y (512) --------
    int c0 = y * 512;
    if (x * 256 >= N || c0 >= kc) return;   // uniform early-exit
    int c1 = min(c0 + 512, kc);
    int t = x * 256 + tid;
    bool act = t < N;
    float tx = 0.f, ty = 0.f, tz = 0.f;
    if (act) { tx = txyz[3*t]; ty = txyz[3*t+1]; tz = txyz[3*t+2]; }
    float ntx = -2.f * tx, nty = -2.f * ty, ntz = -2.f * tz;
    float b0 = 3e38f, b1 = 3e38f; int p0 = -1, p1 = -1;
    for (int tb = c0; tb < c1; tb += SCAN_T) {
      int cnt = min(SCAN_T, c1 - tb);
      if (tid < cnt) tile[tid] = klist[tb + tid];
      __syncthreads();
      int c = 0;
      #pragma unroll 4
      for (; c + 2 <= cnt; c += 2) {
        float4 A = tile[c], B = tile[c + 1];
        // monotone surrogate |c|^2 - 2 t.c (argmin-equiv to |t-c|^2)
        float dA = fmaf(ntx, A.x, A.w); dA = fmaf(nty, A.y, dA); dA = fmaf(ntz, A.z, dA);
        float dB = fmaf(ntx, B.x, B.w); dB = fmaf(nty, B.y, dB); dB = fmaf(ntz, B.z, dB);
        if (dA < b0) { b0 = dA; p0 = tb + c; }
        if (dB < b1) { b1 = dB; p1 = tb + c + 1; }
      }
      if (c < cnt) {
        float4 A = tile[c];
        float dA = fmaf(ntx, A.x, A.w); dA = fmaf(nty, A.y, dA); dA = fmaf(ntz, A.z, dA);
        if (dA < b0) { b0 = dA; p0 = tb + c; }
      }
      __syncthreads();
    }
    if (b1 < b0) { b0 = b1; p0 = p1; }
    if (act && p0 >= 0) {
      float4 cd = klist[p0];
      float dx = tx - cd.x, dy = ty - cd.y, dz = tz - cd.z;
      float dtrue = fmaf(dx, dx, fmaf(dy, dy, dz * dz));  // exact (R1-proven)
      ull pack = ((ull)__float_as_uint(dtrue) << 32) | (unsigned int)kidx[p0];
      atomicMin(&tmin[t], pack);
    }
  } else {
    // ---- forward: ALL kept candidates x*256.. vs target chunk (512) -------
    int t0 = (y - YB) * 512;
    if (x * 256 >= kc) return;              // uniform early-exit
    int t1 = min(t0 + 512, N);
    int e = x * 256 + tid;
    bool act = e < kc;
    float cx = 0.f, cy = 0.f, cz = 0.f, c2 = 0.f;
    int l = 0;
    if (act) {
      float4 cd = klist[e];
      cx = cd.x; cy = cd.y; cz = cd.z; c2 = cd.w;
      l = kidx[e];
    }
    float ncx = -2.f * cx, ncy = -2.f * cy, ncz = -2.f * cz;
    float b0 = 3e38f, b1 = 3e38f; int p0 = 0, p1 = 0;
    for (int tb = t0; tb < t1; tb += SCAN_T) {
      int cnt = min(SCAN_T, t1 - tb);
      if (tid < cnt) tile[tid] = ttile[tb + tid];
      __syncthreads();
      int c = 0;
      #pragma unroll 4
      for (; c + 2 <= cnt; c += 2) {
        float4 A = tile[c], B = tile[c + 1];
        float dA = fmaf(ncx, A.x, A.w); dA = fmaf(ncy, A.y, dA); dA = fmaf(ncz, A.z, dA);
        float dB = fmaf(ncx, B.x, B.w); dB = fmaf(ncy, B.y, dB); dB = fmaf(ncz, B.z, dB);
        if (dA < b0) { b0 = dA; p0 = tb + c; }
        if (dB < b1) { b1 = dB; p1 = tb + c + 1; }
      }
      if (c < cnt) {
        float4 A = tile[c];
        float dA = fmaf(ncx, A.x, A.w); dA = fmaf(ncy, A.y, dA); dA = fmaf(ncz, A.z, dA);
        if (dA < b0) { b0 = dA; p0 = tb + c; }
      }
      __syncthreads();
    }
    if (b1 < b0) { b0 = b1; p0 = p1; }
    if (act) {
      float dkey = fmaxf(b0 + c2, 0.f);   // consistent merge key (R3-proven)
      ull pack = ((ull)__float_as_uint(dkey) << 32) | (unsigned int)p0;
      atomicMin(&fmin[l], pack);
    }
  }
}

// ---- Kernel 4: scatter (blocks 0..NS-1) then loss (all blocks, after spin) -
// Scatter side-effects are ALL atomics -> L2-coherent; 1 fence+counter per
// scatter block (40 total, not R7's 850k). Loss reads intra-kernel data via
// device-scope atomic loads (bypass L1).
__global__ __launch_bounds__(256) void k_scatterloss(
    const float* __restrict__ trgb, const float* __restrict__ crgb,
    const ull* __restrict__ tmin, const ull* __restrict__ fmin,
    const int* __restrict__ keep, float4* __restrict__ numden,
    int* __restrict__ zerohit, float4* __restrict__ zcolor,
    int* __restrict__ counters, float* __restrict__ out,
    int L, int N, int NS) {
  int tid = threadIdx.x, bid = blockIdx.x;
  if (bid < NS) {
    int t = bid * 256 + tid;
    if (t < N) {
      ull pack = tmin[t];   // prev-kernel output: plain load safe
      float d = __uint_as_float((unsigned int)(pack >> 32));
      int idx = (int)(pack & 0xFFFFFFFFull);
      float r = trgb[3*t], g = trgb[3*t+1], b = trgb[3*t+2];
      if (d == 0.0f) {
        atomicExch(&zerohit[idx], 1);
        atomicExch(&zcolor[idx].x, r);
        atomicExch(&zcolor[idx].y, g);
        atomicExch(&zcolor[idx].z, b);
      } else {
        float w = 1.0f / sqrtf(fmaxf(d, 1e-30f));
        atomicAdd(&numden[idx].x, r * w);
        atomicAdd(&numden[idx].y, g * w);
        atomicAdd(&numden[idx].z, b * w);
        atomicAdd(&numden[idx].w, w);
      }
    }
    __syncthreads();
    if (tid == 0) { __threadfence(); atomicAdd(&counters[4], 1); }
  }
  // all 64 blocks co-resident (<=256 CUs): bounded spin on 40 producers
  if (tid == 0) {
    while (atomicAdd(&counters[4], 0) < NS) __builtin_amdgcn_s_sleep(2);
  }
  __syncthreads();
  int l = bid * 256 + tid;
  float loss = 0.f;
  if (l < L && keep[l]) {
    float rr, rg, rb;
    int zh = __hip_atomic_load(&zerohit[l], __ATOMIC_RELAXED, __HIP_MEMORY_SCOPE_AGENT);
    if (zh) {
      rr = __hip_atomic_load(&zcolor[l].x, __ATOMIC_RELAXED, __HIP_MEMORY_SCOPE_AGENT);
      rg = __hip_atomic_load(&zcolor[l].y, __ATOMIC_RELAXED, __HIP_MEMORY_SCOPE_AGENT);
      rb = __hip_atomic_load(&zcolor[l].z, __ATOMIC_RELAXED, __HIP_MEMORY_SCOPE_AGENT);
    } else {
      float nx = __hip_atomic_load(&numden[l].x, __ATOMIC_RELAXED, __HIP_MEMORY_SCOPE_AGENT);
      float ny = __hip_atomic_load(&numden[l].y, __ATOMIC_RELAXED, __HIP_MEMORY_SCOPE_AGENT);
      float nz = __hip_atomic_load(&numden[l].z, __ATOMIC_RELAXED, __HIP_MEMORY_SCOPE_AGENT);
      float nw = __hip_atomic_load(&numden[l].w, __ATOMIC_RELAXED, __HIP_MEMORY_SCOPE_AGENT);
      if (nw != 0.f) { rr = nx / nw; rg = ny / nw; rb = nz / nw; }
      else {
        int ti = (int)(fmin[l] & 0xFFFFFFFFull);   // prev-kernel output
        rr = trgb[3*ti]; rg = trgb[3*ti+1]; rb = trgb[3*ti+2];
      }
    }
    float sr = crgb[3*l]*255.f, sg = crgb[3*l+1]*255.f, sb = crgb[3*l+2]*255.f;
    loss = fabsf(sr - rr) + fabsf(sg - rg) + fabsf(sb - rb);
  }
  for (int o = 32; o > 0; o >>= 1) loss += __shfl_down(loss, o);
  if ((tid & 63) == 0) atomicAdd(&out[1], loss);
}

extern "C" void kernel_launch(void* const* d_in, const int* in_sizes, int n_in,
                              void* d_out, int out_size, void* d_ws, size_t ws_size,
                              hipStream_t stream) {
  const float* pred = (const float*)d_in[0];
  const float* cxyz = (const float*)d_in[1];
  const float* crgb = (const float*)d_in[2];
  const float* txyz = (const float*)d_in[3];
  const float* trgb = (const float*)d_in[4];
  const int*   ktgt = (const int*)d_in[5];
  const int*   pnum = (const int*)d_in[6];
  int L = in_sizes[0];
  int N = in_sizes[3] / 3;

  // workspace layout: 16B arrays first, then 8B, 4B, bytes
  char* ws = (char*)d_ws;
  size_t off = 0;
  float4* klist  = (float4*)(ws + off);   off += (size_t)L * 16;
  float4* ttile  = (float4*)(ws + off);   off += (size_t)((N + 3) & ~3) * 16;
  float4* numden = (float4*)(ws + off);   off += (size_t)L * 16;
  float4* zcolor = (float4*)(ws + off);   off += (size_t)L * 16;
  unsigned int* key = (unsigned int*)(ws + off); off += (size_t)L * 4;  // uint4-aligned
  ull* tmin      = (ull*)(ws + off);      off += (size_t)((N + 1) & ~1) * 8;
  ull* fmin      = (ull*)(ws + off);      off += (size_t)L * 8;
  int* keep      = (int*)(ws + off);      off += (size_t)L * 4;
  int* kidx      = (int*)(ws + off);      off += (size_t)L * 4;
  int* zerohit   = (int*)(ws + off);      off += (size_t)L * 4;
  unsigned int* thrbits = (unsigned int*)(ws + off); off += 16;
  unsigned int* flag = (unsigned int*)(ws + off);    off += 16;
  int* counters  = (int*)(ws + off);      off += 256;   // [0]=kcount [4]=done
  unsigned char* islm = (unsigned char*)(ws + off); off += ((size_t)L + 15) & ~15ull;
  float* out = (float*)d_out;

  int nbL = (L + 255) / 256;   // 64
  int nbN = (N + 255) / 256;   // 40
  int YB = (L + 511) / 512;    // 32 kept-chunks (early-exit trims to kc)
  int YF = (N + 511) / 512;    // 20 target-chunks
  int mx = max(L, N);

  k_prep<<<(mx + 255) / 256, 256, 0, stream>>>(
      pred, txyz, ttile, numden, zerohit, tmin, fmin, key, islm, counters, out, L, N);

  k_selkeep<<<nbL, 256, 0, stream>>>(
      pred, key, islm, pnum, cxyz, ktgt, keep, klist, kidx,
      counters, thrbits, flag, out, L);

  dim3 gs(nbL, YB + YF);
  k_scan2<<<gs, SCAN_T, 0, stream>>>(
      txyz, klist, kidx, ttile, counters, tmin, fmin, L, N, YB);

  k_scatterloss<<<nbL, 256, 0, stream>>>(
      trgb, crgb, tmin, fmin, keep, numden, zerohit, zcolor,
      counters, out, L, N, nbN);
}

// Round 10
// 144.110 us; speedup vs baseline: 1.0765x; 1.0765x over previous
//
#include <hip/hip_runtime.h>
#include <hip/hip_bf16.h>

// Decoder loss: keep-mask (kth-value threshold + local max), BCE coord loss,
// bidirectional NN recolor + L1 rgb loss.
// L=16384 candidates, N=10000 targets, K=8 (collapses to argmin; R1-proven).
// R10: R8 chain + transposed scan. Rules learned on this part:
//   - grid.sync ~40us (R4); mass __threadfence ~0.4ms (R7); spin-fusion ~
//     neutral (R9). Kernel boundary ~4-5us is the cheap sync.
//   - Broadcast LDS scan is ds_read-throughput-bound (~12cyc/16B/wave, R8/R9).
//     Transposed scan (lanes over candidates, wave owns 4 queries) amortizes
//     one LDS read over 64 evals -> VALU-bound, no atomics, no min-init.
//   - Manual 2-chain ILP beat by compiler unroll (R9: +35% time). Keep simple.

#define CH 1024      // staged chunk (16 KB LDS)
typedef unsigned long long ull;

// ---- Kernel 1: init + monotone keys + per-8 local max ----------------------
__global__ __launch_bounds__(256) void k_prep(
    const float* __restrict__ pred, const float* __restrict__ txyz,
    float4* __restrict__ ttile, float4* __restrict__ numden,
    int* __restrict__ zerohit, unsigned int* __restrict__ key,
    unsigned char* __restrict__ islm, int* __restrict__ counters,
    float* __restrict__ out, int L, int N) {
  int gidx = blockIdx.x * 256 + threadIdx.x;
  int gsz = (int)gridDim.x * 256;
  for (int i = gidx; i < N; i += gsz) {
    float x = txyz[3*i], y = txyz[3*i+1], z = txyz[3*i+2];
    ttile[i] = make_float4(x, y, z, fmaf(x, x, fmaf(y, y, z * z)));
  }
  for (int i = gidx; i < L; i += gsz) {
    numden[i] = make_float4(0.f, 0.f, 0.f, 0.f);
    zerohit[i] = 0;
  }
  if (gidx < 8) counters[gidx] = 0;
  if (gidx < 2) out[gidx] = 0.f;
  int ngroups = L >> 3;
  for (int g = gidx; g < ngroups; g += gsz) {
    const float4* pv = (const float4*)pred + (size_t)g * 2;
    float4 a = pv[0], b = pv[1];
    float v[8] = {a.x, a.y, a.z, a.w, b.x, b.y, b.z, b.w};
    int bi = 0; float bv = v[0];
    #pragma unroll
    for (int j = 1; j < 8; ++j) if (v[j] > bv) { bv = v[j]; bi = j; }
    unsigned int kk[8];
    ull lmpack = 0ull;
    #pragma unroll
    for (int j = 0; j < 8; ++j) {
      unsigned int fb = __float_as_uint(v[j]);
      unsigned int mk = (fb & 0x80000000u) ? ~fb : (fb | 0x80000000u);
      if (j == bi) { mk = 0xFF800000u; lmpack |= 1ull << (8 * j); }  // +inf
      kk[j] = mk;
    }
    ((uint4*)key)[g*2]   = make_uint4(kk[0], kk[1], kk[2], kk[3]);
    ((uint4*)key)[g*2+1] = make_uint4(kk[4], kk[5], kk[6], kk[7]);
    *(ull*)(islm + (size_t)g * 8) = lmpack;
  }
}

// ---- helper: pick bin containing rank from LDS hist (wave 0) ---------------
__device__ __forceinline__ void select_bin(
    unsigned int* hist, int nb, unsigned int rank,
    unsigned int* sB, unsigned int* sR, int tid) {
  if (tid < 64) {
    int g = nb >> 6;
    unsigned int sum = 0;
    for (int j = 0; j < g; ++j) sum += hist[tid * g + j];
    unsigned int incl = sum;
    for (int o = 1; o < 64; o <<= 1) {
      unsigned int v = __shfl_up(incl, o);
      if (tid >= o) incl += v;
    }
    unsigned int excl = incl - sum;
    bool cond = (rank >= excl) && (rank < incl);
    unsigned long long bal = __ballot(cond);
    int first = __ffsll((long long)bal) - 1;
    if (tid == first) {
      unsigned int r = rank - excl, cum = 0;
      for (int j = 0; j < g; ++j) {
        unsigned int c = hist[tid * g + j];
        if (r < cum + c) { *sB = (unsigned int)(tid * g + j); *sR = r - cum; break; }
        cum += c;
      }
    }
  }
}

// ---- Kernel 2: exact rank select, self-contained (1 block, 3 sweeps) -------
__global__ __launch_bounds__(256) void k_sel(
    const unsigned int* __restrict__ key, const int* __restrict__ pnum_p,
    float* __restrict__ thr_out, int L) {
  __shared__ unsigned int hist[2048];
  __shared__ unsigned int sB, sR;
  int tid = threadIdx.x;
  unsigned int rank = (unsigned int)(L - pnum_p[0] - 1);
  const uint4* k4 = (const uint4*)key;
  int n4 = L >> 2;
  for (int b = tid; b < 2048; b += 256) hist[b] = 0u;
  __syncthreads();
  for (int i = tid; i < n4; i += 256) {
    uint4 v = k4[i];
    atomicAdd(&hist[v.x >> 21], 1u); atomicAdd(&hist[v.y >> 21], 1u);
    atomicAdd(&hist[v.z >> 21], 1u); atomicAdd(&hist[v.w >> 21], 1u);
  }
  __syncthreads();
  select_bin(hist, 2048, rank, &sB, &sR, tid);
  __syncthreads();
  unsigned int B1 = sB, R1 = sR;
  for (int b = tid; b < 2048; b += 256) hist[b] = 0u;
  __syncthreads();
  for (int i = tid; i < n4; i += 256) {
    uint4 v = k4[i];
    if ((v.x >> 21) == B1) atomicAdd(&hist[(v.x >> 10) & 2047u], 1u);
    if ((v.y >> 21) == B1) atomicAdd(&hist[(v.y >> 10) & 2047u], 1u);
    if ((v.z >> 21) == B1) atomicAdd(&hist[(v.z >> 10) & 2047u], 1u);
    if ((v.w >> 21) == B1) atomicAdd(&hist[(v.w >> 10) & 2047u], 1u);
  }
  __syncthreads();
  select_bin(hist, 2048, R1, &sB, &sR, tid);
  __syncthreads();
  unsigned int B2 = sB, R2 = sR;
  for (int b = tid; b < 1024; b += 256) hist[b] = 0u;
  __syncthreads();
  unsigned int top22 = (B1 << 11) | B2;
  for (int i = tid; i < n4; i += 256) {
    uint4 v = k4[i];
    if ((v.x >> 10) == top22) atomicAdd(&hist[v.x & 1023u], 1u);
    if ((v.y >> 10) == top22) atomicAdd(&hist[v.y & 1023u], 1u);
    if ((v.z >> 10) == top22) atomicAdd(&hist[v.z & 1023u], 1u);
    if ((v.w >> 10) == top22) atomicAdd(&hist[v.w & 1023u], 1u);
  }
  __syncthreads();
  select_bin(hist, 1024, R2, &sB, &sR, tid);
  __syncthreads();
  if (tid == 0) {
    unsigned int fkey = (B1 << 21) | (B2 << 10) | sB;
    unsigned int fb = (fkey & 0x80000000u) ? (fkey & 0x7FFFFFFFu) : ~fkey;
    thr_out[0] = __uint_as_float(fb);
  }
}

// ---- Kernel 3: keep mask + compaction + BCE reduce -------------------------
__global__ __launch_bounds__(256) void k_keepc(
    const float* __restrict__ pred, const unsigned char* __restrict__ islm,
    const float* __restrict__ thr_p, const float* __restrict__ cxyz,
    const int* __restrict__ ktgt, int* __restrict__ keep,
    float4* __restrict__ klist, int* __restrict__ kidx,
    int* __restrict__ counters, float* __restrict__ out, int L) {
  int i = blockIdx.x * 256 + threadIdx.x;
  float thr = thr_p[0];
  float term = 0.f;
  if (i < L) {
    float p = pred[i];
    bool kp = (p > thr) || islm[i];
    keep[i] = kp ? 1 : 0;
    if (kp) {
      int pos = atomicAdd(&counters[0], 1);   // order irrelevant (no ties)
      float x = cxyz[3*i], y = cxyz[3*i+1], z = cxyz[3*i+2];
      klist[pos] = make_float4(x, y, z, fmaf(x, x, fmaf(y, y, z * z)));
      kidx[pos] = i;
    }
    float t = (float)ktgt[i];
    term = fmaxf(p, 0.f) - p * t + log1pf(expf(-fabsf(p)));
  }
  for (int o = 32; o > 0; o >>= 1) term += __shfl_down(term, o);
  if ((threadIdx.x & 63) == 0) atomicAdd(&out[0], term);
}

// ---- Kernel 4: transposed dual-role scan -----------------------------------
// Wave owns 4 query points; lanes sweep the staged list (1 ds_read_b128 per
// 64 evals). Single-owner reduction -> plain stores, no atomics, no init.
__global__ __launch_bounds__(256) void k_scanw(
    const float* __restrict__ txyz, const float4* __restrict__ klist,
    const int* __restrict__ kidx, const float4* __restrict__ ttile,
    const int* __restrict__ counters, ull* __restrict__ tmin,
    int* __restrict__ fidx, int L, int N, int NBW) {
  __shared__ float4 sb[CH];
  int tid = threadIdx.x;
  int lane = tid & 63;
  int wv = tid >> 6;
  int kc = counters[0];
  int bid = blockIdx.x;

  float q0x, q0y, q0z, q1x, q1y, q1z, q2x, q2y, q2z, q3x, q3y, q3z;
  const float4* list; int listn; int q0;
  if (bid < NBW) {           // backward: queries = targets, list = klist
    q0 = bid * 16 + wv * 4;
    int a = min(q0, N - 1), b = min(q0 + 1, N - 1),
        c = min(q0 + 2, N - 1), d = min(q0 + 3, N - 1);
    q0x = txyz[3*a]; q0y = txyz[3*a+1]; q0z = txyz[3*a+2];
    q1x = txyz[3*b]; q1y = txyz[3*b+1]; q1z = txyz[3*b+2];
    q2x = txyz[3*c]; q2y = txyz[3*c+1]; q2z = txyz[3*c+2];
    q3x = txyz[3*d]; q3y = txyz[3*d+1]; q3z = txyz[3*d+2];
    list = klist; listn = kc;
  } else {                   // forward: queries = kept candidates, list = ttile
    int eb = (bid - NBW) * 16;
    if (eb >= kc) return;    // uniform early-exit
    q0 = eb + wv * 4;
    int a = min(q0, kc - 1), b = min(q0 + 1, kc - 1),
        c = min(q0 + 2, kc - 1), d = min(q0 + 3, kc - 1);
    float4 A = klist[a], B = klist[b], C = klist[c], D = klist[d];
    q0x = A.x; q0y = A.y; q0z = A.z;
    q1x = B.x; q1y = B.y; q1z = B.z;
    q2x = C.x; q2y = C.y; q2z = C.z;
    q3x = D.x; q3y = D.y; q3z = D.z;
    list = ttile; listn = N;
  }
  float n0x = -2.f*q0x, n0y = -2.f*q0y, n0z = -2.f*q0z;
  float n1x = -2.f*q1x, n1y = -2.f*q1y, n1z = -2.f*q1z;
  float n2x = -2.f*q2x, n2y = -2.f*q2y, n2z = -2.f*q2z;
  float n3x = -2.f*q3x, n3y = -2.f*q3y, n3z = -2.f*q3z;
  float b0 = 3e38f, b1 = 3e38f, b2 = 3e38f, b3 = 3e38f;
  int i0 = 0, i1 = 0, i2 = 0, i3 = 0;

  for (int tile = 0; tile < listn; tile += CH) {
    int cnt = min(CH, listn - tile);
    int cntp = (cnt + 63) & ~63;
    for (int j = tid; j < cntp; j += 256)
      sb[j] = (j < cnt) ? list[tile + j] : make_float4(0.f, 0.f, 0.f, 3e38f);
    __syncthreads();
    #pragma unroll 2
    for (int i = lane; i < cntp; i += 64) {
      float4 A = sb[i];
      int c = tile + i;
      // monotone surrogate |p|^2 - 2 q.p (argmin-equiv to |q-p|^2)
      float d0 = fmaf(n0x, A.x, A.w); d0 = fmaf(n0y, A.y, d0); d0 = fmaf(n0z, A.z, d0);
      float d1 = fmaf(n1x, A.x, A.w); d1 = fmaf(n1y, A.y, d1); d1 = fmaf(n1z, A.z, d1);
      float d2 = fmaf(n2x, A.x, A.w); d2 = fmaf(n2y, A.y, d2); d2 = fmaf(n2z, A.z, d2);
      float d3 = fmaf(n3x, A.x, A.w); d3 = fmaf(n3y, A.y, d3); d3 = fmaf(n3z, A.z, d3);
      if (d0 < b0) { b0 = d0; i0 = c; }
      if (d1 < b1) { b1 = d1; i1 = c; }
      if (d2 < b2) { b2 = d2; i2 = c; }
      if (d3 < b3) { b3 = d3; i3 = c; }
    }
    __syncthreads();
  }
  // wave argmin reduce (prefer lower index on exact tie, matching jnp)
  #pragma unroll
  for (int o = 32; o > 0; o >>= 1) {
    float ob; int oi;
    ob = __shfl_xor(b0, o); oi = __shfl_xor(i0, o);
    if (ob < b0 || (ob == b0 && oi < i0)) { b0 = ob; i0 = oi; }
    ob = __shfl_xor(b1, o); oi = __shfl_xor(i1, o);
    if (ob < b1 || (ob == b1 && oi < i1)) { b1 = ob; i1 = oi; }
    ob = __shfl_xor(b2, o); oi = __shfl_xor(i2, o);
    if (ob < b2 || (ob == b2 && oi < i2)) { b2 = ob; i2 = oi; }
    ob = __shfl_xor(b3, o); oi = __shfl_xor(i3, o);
    if (ob < b3 || (ob == b3 && oi < i3)) { b3 = ob; i3 = oi; }
  }
  if (lane == 0) {
    int ii[4] = {i0, i1, i2, i3};
    if (bid < NBW) {
      #pragma unroll
      for (int j = 0; j < 4; ++j) {
        int t = q0 + j;
        if (t < N) {
          float4 cd = klist[ii[j]];
          float dx = txyz[3*t] - cd.x, dy = txyz[3*t+1] - cd.y, dz = txyz[3*t+2] - cd.z;
          float dtrue = fmaf(dx, dx, fmaf(dy, dy, dz * dz));  // exact (R1-proven)
          tmin[t] = ((ull)__float_as_uint(dtrue) << 32) | (unsigned int)kidx[ii[j]];
        }
      }
    } else {
      #pragma unroll
      for (int j = 0; j < 4; ++j) {
        int e = q0 + j;
        if (e < kc) fidx[kidx[e]] = ii[j];
      }
    }
  }
}

// ---- Kernel 5: scatter weighted colors into num/den ------------------------
__global__ __launch_bounds__(256) void k_scatter(
    const float* __restrict__ trgb, const ull* __restrict__ tmin,
    float4* __restrict__ numden, int* __restrict__ zerohit,
    float4* __restrict__ zcolor, int N) {
  int t = blockIdx.x * 256 + threadIdx.x;
  if (t >= N) return;
  ull pack = tmin[t];
  float d = __uint_as_float((unsigned int)(pack >> 32));
  int idx = (int)(pack & 0xFFFFFFFFull);
  float r = trgb[3*t], g = trgb[3*t+1], b = trgb[3*t+2];
  if (d == 0.0f) {
    zerohit[idx] = 1;
    zcolor[idx] = make_float4(r, g, b, 0.f);
  } else {
    float w = 1.0f / sqrtf(fmaxf(d, 1e-30f));
    atomicAdd(&numden[idx].x, r * w);
    atomicAdd(&numden[idx].y, g * w);
    atomicAdd(&numden[idx].z, b * w);
    atomicAdd(&numden[idx].w, w);
  }
}

// ---- Kernel 6: final recolor select + L1 reduce ----------------------------
__global__ __launch_bounds__(256) void k_loss(
    const float* __restrict__ crgb, const float* __restrict__ trgb,
    const int* __restrict__ keep, const float4* __restrict__ numden,
    const int* __restrict__ zerohit, const float4* __restrict__ zcolor,
    const int* __restrict__ fidx, float* __restrict__ out, int L) {
  int l = blockIdx.x * 256 + threadIdx.x;
  float loss = 0.f;
  if (l < L && keep[l]) {
    float rr, rg, rb;
    if (zerohit[l]) {
      float4 z = zcolor[l]; rr = z.x; rg = z.y; rb = z.z;
    } else {
      float4 nd = numden[l];
      if (nd.w != 0.f) { rr = nd.x / nd.w; rg = nd.y / nd.w; rb = nd.z / nd.w; }
      else {
        int ti = fidx[l];
        rr = trgb[3*ti]; rg = trgb[3*ti+1]; rb = trgb[3*ti+2];
      }
    }
    float sr = crgb[3*l]*255.f, sg = crgb[3*l+1]*255.f, sb = crgb[3*l+2]*255.f;
    loss = fabsf(sr - rr) + fabsf(sg - rg) + fabsf(sb - rb);
  }
  for (int o = 32; o > 0; o >>= 1) loss += __shfl_down(loss, o);
  if ((threadIdx.x & 63) == 0) atomicAdd(&out[1], loss);
}

extern "C" void kernel_launch(void* const* d_in, const int* in_sizes, int n_in,
                              void* d_out, int out_size, void* d_ws, size_t ws_size,
                              hipStream_t stream) {
  const float* pred = (const float*)d_in[0];
  const float* cxyz = (const float*)d_in[1];
  const float* crgb = (const float*)d_in[2];
  const float* txyz = (const float*)d_in[3];
  const float* trgb = (const float*)d_in[4];
  const int*   ktgt = (const int*)d_in[5];
  const int*   pnum = (const int*)d_in[6];
  int L = in_sizes[0];
  int N = in_sizes[3] / 3;

  // workspace layout: 16B arrays first, then 8B, 4B, bytes
  char* ws = (char*)d_ws;
  size_t off = 0;
  float4* klist  = (float4*)(ws + off);   off += (size_t)L * 16;
  float4* ttile  = (float4*)(ws + off);   off += (size_t)((N + 3) & ~3) * 16;
  float4* numden = (float4*)(ws + off);   off += (size_t)L * 16;
  float4* zcolor = (float4*)(ws + off);   off += (size_t)L * 16;
  unsigned int* key = (unsigned int*)(ws + off); off += (size_t)L * 4;  // uint4-aligned
  ull* tmin      = (ull*)(ws + off);      off += (size_t)((N + 1) & ~1) * 8;
  int* keep      = (int*)(ws + off);      off += (size_t)L * 4;
  int* kidx      = (int*)(ws + off);      off += (size_t)L * 4;
  int* zerohit   = (int*)(ws + off);      off += (size_t)L * 4;
  int* fidx      = (int*)(ws + off);      off += (size_t)L * 4;
  float* thr_slot = (float*)(ws + off);   off += 16;
  int* counters  = (int*)(ws + off);      off += 256;   // [0]=kcount
  unsigned char* islm = (unsigned char*)(ws + off); off += ((size_t)L + 15) & ~15ull;
  float* out = (float*)d_out;

  int nbL = (L + 255) / 256;     // 64
  int nbN = (N + 255) / 256;     // 40
  int NBW = (N + 15) / 16;       // 625 backward blocks (16 queries each)
  int NFW = (L + 15) / 16;       // 1024 forward blocks max (early-exit at kc)
  int mx = max(L, N);

  k_prep<<<(mx + 255) / 256, 256, 0, stream>>>(
      pred, txyz, ttile, numden, zerohit, key, islm, counters, out, L, N);

  k_sel<<<1, 256, 0, stream>>>(key, pnum, thr_slot, L);

  k_keepc<<<nbL, 256, 0, stream>>>(
      pred, islm, thr_slot, cxyz, ktgt, keep, klist, kidx, counters, out, L);

  k_scanw<<<NBW + NFW, 256, 0, stream>>>(
      txyz, klist, kidx, ttile, counters, tmin, fidx, L, N, NBW);

  k_scatter<<<nbN, 256, 0, stream>>>(trgb, tmin, numden, zerohit, zcolor, N);

  k_loss<<<nbL, 256, 0, stream>>>(
      crgb, trgb, keep, numden, zerohit, zcolor, fidx, out, L);
}